// Round 12
// baseline (3429.300 us; speedup 1.0000x reference)
//
#include <hip/hip_runtime.h>

// ---------------------------------------------------------------------------
// 2-layer LSTM (H=51) + Linear(51,1), B=1024, T=1024, fp32.
// Design (R12): 16 lanes/unit -> 48 weight floats/lane (fits ARCH VGPRs).
//   R9-R11 evidence: at 96 weights/lane the backend always parks weights in
//   AGPRs (VGPR_Count 64/88) and v_accvgpr_read copies ~double the issue
//   count. Halving per-lane weight footprint removes the fight entirely.
//   - 1024 thr/block (64 units x 16 lanes), 256 blocks, BPB=4 -> ONE
//     generation, 4 waves/SIMD (R11 had only 2 -> poor latency hiding).
//   - lane (a=tid>>4, c=tid&15): elements [4c,4c+4) of rows {g*51+a};
//     per gate 2 f2 -> 3 matrices x 8 f2 = 48 VGPRs.
//   - reduce: quad transpose-butterfly (lane q=c&3 owns gate q) then
//     __shfl_xor 4 + 8 across the unit's 4 sub-chunks.
//   - single barrier/step, L2 one step behind L1, ping-pong h buffers,
//     in-quad DPP c/h update, v_pk asm dots, y deferred on spare units
//     51..54 (tid 816..879), branchless k==0 mask. [R9-R11-proven]
// ---------------------------------------------------------------------------

#define H    51
#define TLEN 1024
#define BPB  4
#define NTHR 1024
#define NBLK 256

typedef __attribute__((ext_vector_type(2))) float f2;
typedef __attribute__((ext_vector_type(4))) float f4;

__device__ __forceinline__ float frcp(float x) { return __builtin_amdgcn_rcpf(x); }

// packed fp32: D = A*B (+D). 64-bit VGPR-pair operands.
#define PKMUL(D, A, B) asm("v_pk_mul_f32 %0, %1, %2"     : "=v"(D) : "v"(A), "v"(B))
#define PKFMA(D, A, B) asm("v_pk_fma_f32 %0, %1, %2, %0" : "+v"(D) : "v"(A), "v"(B))

// quad_perm DPP: 0xB1=[1,0,3,2] xor1, 0x4E=[2,3,0,1] xor2,
// 0x00=bcast lane0, 0x55=bcast lane1.
#define DPP_GET(X, CTRL)  (__int_as_float(__builtin_amdgcn_update_dpp(       \
                              0, __float_as_int(X), CTRL, 0xF, 0xF, true)))
#define DPP_XADD(X, CTRL) ((X) + DPP_GET(X, CTRL))

// quad transpose-butterfly + cross-subchunk combine: lane q=c&3 ends with
// the full 64-element sum for gate q. t0..t3 are this lane's 4 gate partials.
#define UNIT_REDUCE(SEL, T0, T1, T2, T3)                                     \
    {                                                                        \
        const float s01 = (q & 1) ? T0 : T1, o01 = (q & 1) ? T1 : T0;        \
        const float s23 = (q & 1) ? T2 : T3, o23 = (q & 1) ? T3 : T2;        \
        const float aa = o01 + DPP_GET(s01, 0xB1);                           \
        const float bb = o23 + DPP_GET(s23, 0xB1);                           \
        const float yv = (q & 2) ? aa : bb, ov = (q & 2) ? bb : aa;          \
        float s = ov + DPP_GET(yv, 0x4E);                                    \
        s += __shfl_xor(s, 4);                                               \
        s += __shfl_xor(s, 8);                                               \
        SEL = s;                                                             \
    }

__global__
__attribute__((amdgpu_flat_work_group_size(NTHR, NTHR), amdgpu_waves_per_eu(4, 4)))
void lstm2_kernel(const float* __restrict__ input,
                  const float* __restrict__ W_ih1, const float* __restrict__ W_hh1,
                  const float* __restrict__ b_ih1, const float* __restrict__ b_hh1,
                  const float* __restrict__ W_ih2, const float* __restrict__ W_hh2,
                  const float* __restrict__ b_ih2, const float* __restrict__ b_hh2,
                  const float* __restrict__ W_lin, const float* __restrict__ b_lin,
                  float* __restrict__ out)
{
    const int tid = threadIdx.x;
    const int b0  = blockIdx.x * BPB;
    const int a   = tid >> 4;        // unit 0..63 (a<51 active)
    const int c   = tid & 15;        // k-subchunk lane: elements [4c, 4c+4)
    const int q   = c & 3;           // after reduce, this lane owns gate q
    const bool ul = (a < H);

    __shared__ __align__(16) float h1buf[BPB][2][64];   // [batch][pingpong]
    __shared__ __align__(16) float h2buf[BPB][2][64];
    __shared__ __align__(16) float sh_wl[64];           // W_lin, zero-padded

    if (tid < 512)       ((float*)h1buf)[tid] = 0.0f;   // BPB*2*64 == 512
    else                 ((float*)h2buf)[tid - 512] = 0.0f;
    if (tid < 64) sh_wl[tid] = (tid < H) ? W_lin[tid] : 0.0f;

    // per-lane weights: rows g*51+a, elements [4c, 4c+4), zero-padded
    f2 w1[8], wi2[8], wh2[8];
#pragma unroll
    for (int g = 0; g < 4; ++g) {
#pragma unroll
        for (int j = 0; j < 2; ++j) {
            const int e0 = c * 4 + 2 * j, e1 = e0 + 1;
            const int r  = g * H + a;
            const bool v0 = ul && (e0 < H), v1 = ul && (e1 < H);
            w1 [g*2+j] = f2{v0 ? W_hh1[r*H+e0] : 0.f, v1 ? W_hh1[r*H+e1] : 0.f};
            wi2[g*2+j] = f2{v0 ? W_ih2[r*H+e0] : 0.f, v1 ? W_ih2[r*H+e1] : 0.f};
            wh2[g*2+j] = f2{v0 ? W_hh2[r*H+e0] : 0.f, v1 ? W_hh2[r*H+e1] : 0.f};
        }
    }
    asm volatile("" : "+v"(w1[0]), "+v"(w1[1]), "+v"(w1[2]), "+v"(w1[3]),
                      "+v"(w1[4]), "+v"(w1[5]), "+v"(w1[6]), "+v"(w1[7]));
    asm volatile("" : "+v"(wi2[0]), "+v"(wi2[1]), "+v"(wi2[2]), "+v"(wi2[3]),
                      "+v"(wi2[4]), "+v"(wi2[5]), "+v"(wi2[6]), "+v"(wi2[7]));
    asm volatile("" : "+v"(wh2[0]), "+v"(wh2[1]), "+v"(wh2[2]), "+v"(wh2[3]),
                      "+v"(wh2[4]), "+v"(wh2[5]), "+v"(wh2[6]), "+v"(wh2[7]));

    const int rq = q * H + a;                      // this lane's own gate row
    const float wx  = ul ? W_ih1[rq] : 0.f;
    const float bb1 = ul ? (b_ih1[rq] + b_hh1[rq]) : 0.f;
    const float bb2 = ul ? (b_ih2[rq] + b_hh2[rq]) : 0.f;
    const float sm  = (q == 2) ? -2.0f : -1.0f;    // tanh gate as scaled sigmoid
    const float bm  = (q == 2) ? -1.0f :  0.0f;    // act = sg + bm*(1-sg)

    const int  sj    = tid - 816;                  // y lanes: units 51..54
    const bool ylane = ((unsigned)sj < (unsigned)(16 * BPB));
    const int  yb    = (sj >> 4) & (BPB - 1);      // batch handled by group
    const int  sjj   = sj & 15;
    const float blin = b_lin[0];

    float c1[BPB], c2[BPB];
#pragma unroll
    for (int n = 0; n < BPB; ++n) { c1[n] = 0.0f; c2[n] = 0.0f; }

    __syncthreads();                               // zeros + sh_wl visible

    for (int k = 0; k <= TLEN; ++k) {
        const int rb = (k + 1) & 1;                // holds h1(k-1), h2(k-2)
        const int wb = k & 1;
        const int kx = (k < TLEN) ? k : TLEN - 1;
        const float km = (k == 0) ? 0.0f : 1.0f;   // L2 step k-1 validity mask

        // ---- deferred y(k-2): 4 spare 16-lane groups, one per batch ----
        if (ylane && k >= 2) {
            const f4 hv = *(const f4*)&h2buf[yb][rb][sjj * 4];
            const f4 wl = *(const f4*)&sh_wl[sjj * 4];
            float yp = hv.x*wl.x + hv.y*wl.y + hv.z*wl.z + hv.w*wl.w;
            yp = DPP_XADD(yp, 0xB1);  yp = DPP_XADD(yp, 0x4E);
            yp += __shfl_xor(yp, 4);  yp += __shfl_xor(yp, 8);
            if (sjj == 0) out[(size_t)(b0 + yb) * TLEN + (k - 2)] = yp + blin;
        }

        // ---- 4 batches sequentially (weights arch-resident, reused) ----
#pragma unroll
        for (int n = 0; n < BPB; ++n) {
            const float x = input[(size_t)(b0 + n) * TLEN + kx];

            const f4 A = *(const f4*)&h1buf[n][rb][c * 4];
            const f4 B = *(const f4*)&h2buf[n][rb][c * 4];
            const f2 al = f2{A.x, A.y}, ah = f2{A.z, A.w};
            const f2 bl = f2{B.x, B.y}, bh = f2{B.z, B.w};

            // L1 per-gate partial dots (2 pk each)
            f2 p0, p1, p2, p3;
            PKMUL(p0, w1[0], al); PKFMA(p0, w1[1], ah);
            PKMUL(p1, w1[2], al); PKFMA(p1, w1[3], ah);
            PKMUL(p2, w1[4], al); PKFMA(p2, w1[5], ah);
            PKMUL(p3, w1[6], al); PKFMA(p3, w1[7], ah);
            float t0 = p0.x + p0.y, t1 = p1.x + p1.y,
                  t2 = p2.x + p2.y, t3 = p3.x + p3.y;
            float sel1;
            UNIT_REDUCE(sel1, t0, t1, t2, t3);

            // L2 per-gate partial dots: wi2.h1(k-1) + wh2.h2(k-2) (4 pk each)
            PKMUL(p0, wi2[0], al); PKFMA(p0, wi2[1], ah);
            PKFMA(p0, wh2[0], bl); PKFMA(p0, wh2[1], bh);
            PKMUL(p1, wi2[2], al); PKFMA(p1, wi2[3], ah);
            PKFMA(p1, wh2[2], bl); PKFMA(p1, wh2[3], bh);
            PKMUL(p2, wi2[4], al); PKFMA(p2, wi2[5], ah);
            PKFMA(p2, wh2[4], bl); PKFMA(p2, wh2[5], bh);
            PKMUL(p3, wi2[6], al); PKFMA(p3, wi2[7], ah);
            PKFMA(p3, wh2[6], bl); PKFMA(p3, wh2[7], bh);
            t0 = p0.x + p0.y; t1 = p1.x + p1.y;
            t2 = p2.x + p2.y; t3 = p3.x + p3.y;
            float sel2;
            UNIT_REDUCE(sel2, t0, t1, t2, t3);

            // L1 act + in-quad exchange + c1/h1 update (step k)
            {
                const float pre = sel1 + bb1 + wx * x;
                const float sg  = frcp(1.0f + __expf(sm * pre));
                const float act = sg + bm * (1.0f - sg);   // lane q: gate q
                const float bx  = DPP_GET(act, 0x4E);      // partner (i<->g, f<->o)
                const float p   = act * bx;                // lanes 0,2: i*g
                const float pv  = DPP_GET(p,   0x00);      // bcast i*g
                const float fv  = DPP_GET(act, 0x55);      // bcast f
                c1[n] = fv * c1[n] + pv;
                const float th = 1.0f - 2.0f * frcp(__expf(2.0f * c1[n]) + 1.0f);
                if (ul && c == 3) h1buf[n][wb][a] = act * th;   // q==3: act = o
            }

            // L2 act + exchange + c2/h2 update (step k-1; masked at k=0)
            {
                const float pre = sel2 + bb2;
                const float sg  = frcp(1.0f + __expf(sm * pre));
                const float act = sg + bm * (1.0f - sg);
                const float bx  = DPP_GET(act, 0x4E);
                const float p   = act * bx;
                const float pv  = DPP_GET(p,   0x00);
                const float fv  = DPP_GET(act, 0x55);
                c2[n] = fv * c2[n] + km * pv;              // k=0: c2 stays 0
                const float th = 1.0f - 2.0f * frcp(__expf(2.0f * c2[n]) + 1.0f);
                if (ul && c == 3) h2buf[n][wb][a] = act * th;   // k=0 writes 0
            }
        }

        __syncthreads();                                   // the one barrier
    }

    // epilogue: y(T-1) from h2buf[yb][TLEN & 1] (written at iter k=TLEN)
    if (ylane) {
        const f4 hv = *(const f4*)&h2buf[yb][TLEN & 1][sjj * 4];
        const f4 wl = *(const f4*)&sh_wl[sjj * 4];
        float yp = hv.x*wl.x + hv.y*wl.y + hv.z*wl.z + hv.w*wl.w;
        yp = DPP_XADD(yp, 0xB1);  yp = DPP_XADD(yp, 0x4E);
        yp += __shfl_xor(yp, 4);  yp += __shfl_xor(yp, 8);
        if (sjj == 0) out[(size_t)(b0 + yb) * TLEN + (TLEN - 1)] = yp + blin;
    }
}

extern "C" void kernel_launch(void* const* d_in, const int* in_sizes, int n_in,
                              void* d_out, int out_size, void* d_ws, size_t ws_size,
                              hipStream_t stream)
{
    const float* input = (const float*)d_in[0];
    const float* W_ih1 = (const float*)d_in[1];
    const float* W_hh1 = (const float*)d_in[2];
    const float* b_ih1 = (const float*)d_in[3];
    const float* b_hh1 = (const float*)d_in[4];
    const float* W_ih2 = (const float*)d_in[5];
    const float* W_hh2 = (const float*)d_in[6];
    const float* b_ih2 = (const float*)d_in[7];
    const float* b_hh2 = (const float*)d_in[8];
    const float* W_lin = (const float*)d_in[9];
    const float* b_lin = (const float*)d_in[10];

    float* out = (float*)d_out;

    hipLaunchKernelGGL(lstm2_kernel, dim3(NBLK), dim3(NTHR), 0, stream,
                       input, W_ih1, W_hh1, b_ih1, b_hh1,
                       W_ih2, W_hh2, b_ih2, b_hh2, W_lin, b_lin,
                       out);
}

// Round 14
// 1942.423 us; speedup vs baseline: 1.7655x; 1.7655x over previous
//
#include <hip/hip_runtime.h>

// ---------------------------------------------------------------------------
// 2-layer LSTM (H=51) + Linear(51,1), B=1024, T=1024, fp32.
// Design (R14 = R13 + hi/lo-split h): MFMA engine.
//   R13 failed absmax 1.95e-3 vs 1.66e-3 — precision, not layout (layout bug
//   would be O(1) garbage). Cause: h truncated to single bf16 (2^-9 bias).
//   - h stored in LDS as ONE packed u32 = (bf16_hi << 16) | bf16_lo, RNE
//     split computed once by the producer lane. B-frags: hi and lo fragments
//     via two v_perm byte-selects (0x07060302 / 0x05040100) per u32-pair.
//   - gates = Whi.hhi + Whi.hlo + Wlo.hhi (3 mfma terms; dropped Wlo.hlo
//     ~2^-18 rel). Per-step error ~1e-6 -> absmax back to fp32-class 2.4e-4.
//   - W rows permuted prow=4u+g -> C-layout gives each lane all 4 gates of
//     unit u = 4*tile+quad in its 4 acc regs: LANE-LOCAL c/h update.
//   - 64 blocks x 256 thr (4 waves), 16 batches/block, waves_per_eu(1,1).
//     Wave w owns row-tiles {w, 4+w, 8+w, 12 (w==0)}.
//   - ONE barrier/step, L2 one step behind L1, ping-pong h LDS (stride 17),
//     deferred y on wave 3 (k-2), k==0 guard.   [R9-R13-proven skeleton]
// ---------------------------------------------------------------------------

#define H     51
#define NROW  204      // 4*H
#define TLEN  1024
#define BPB   16       // batches per block (= mfma N)
#define NTHR  256
#define NBLK  64
#define LSTR  17       // LDS row stride

typedef __attribute__((ext_vector_type(8))) short bf16x8;   // 8 bf16 = 4 VGPRs
typedef __attribute__((ext_vector_type(4))) float f4;

__device__ __forceinline__ float frcp(float x) { return __builtin_amdgcn_rcpf(x); }
__device__ __forceinline__ float sigm(float x) { return frcp(1.0f + __expf(-x)); }
__device__ __forceinline__ float tanh_(float x) {
    return 1.0f - 2.0f * frcp(__expf(2.0f * x) + 1.0f);
}

__device__ __forceinline__ short bf_rne(float f) {        // fp32 -> bf16 RNE
    unsigned u = __float_as_uint(f);
    return (short)((u + 0x7FFFu + ((u >> 16) & 1u)) >> 16);
}
__device__ __forceinline__ float bf_f(short h) {          // bf16 -> fp32
    return __uint_as_float(((unsigned)(unsigned short)h) << 16);
}
// RNE hi/lo split of fp32, packed (hi16 << 16) | lo16
__device__ __forceinline__ unsigned pack_hl(float f) {
    unsigned u   = __float_as_uint(f);
    unsigned h16 = (u + 0x7FFFu + ((u >> 16) & 1u)) >> 16;
    float    r   = f - __uint_as_float(h16 << 16);
    unsigned v   = __float_as_uint(r);
    unsigned l16 = (v + 0x7FFFu + ((v >> 16) & 1u)) >> 16;
    return (h16 << 16) | (l16 & 0xFFFFu);
}
__device__ __forceinline__ float unpack_f(unsigned p) {
    return __uint_as_float(p & 0xFFFF0000u) + __uint_as_float(p << 16);
}

#define MFMA(ACC, A, B) \
    ACC = __builtin_amdgcn_mfma_f32_16x16x32_bf16((A), (B), (ACC), 0, 0, 0)

// A-frag for 16x16x32: lane holds A[m=lane&15][k=quad*8+j], j=0..7.
// Source W is [204][51] row-major, PyTorch rows g*51+u; permuted row
// prow = 4u+g -> src row = (prow&3)*51 + (prow>>2). Zero-pad prow>=204, k>=51.
__device__ __forceinline__ void load_wfrag(const float* __restrict__ W,
                                           int tile, int kt, int q, int mcol,
                                           bf16x8* hi, bf16x8* lo)
{
    bf16x8 h, l;
    const int prow = tile * 16 + mcol;
#pragma unroll
    for (int j = 0; j < 8; ++j) {
        const int kk = kt * 32 + q * 8 + j;
        float v = 0.0f;
        if (prow < NROW && kk < H) {
            const int srow = (prow & 3) * H + (prow >> 2);
            v = W[srow * H + kk];
        }
        const short hb = bf_rne(v);
        h[j] = hb;
        l[j] = bf_rne(v - bf_f(hb));
    }
    *hi = h;
    *lo = l;
}

__global__
__attribute__((amdgpu_flat_work_group_size(NTHR, NTHR), amdgpu_waves_per_eu(1, 1)))
void lstm2_kernel(const float* __restrict__ input,
                  const float* __restrict__ W_ih1, const float* __restrict__ W_hh1,
                  const float* __restrict__ b_ih1, const float* __restrict__ b_hh1,
                  const float* __restrict__ W_ih2, const float* __restrict__ W_hh2,
                  const float* __restrict__ b_ih2, const float* __restrict__ b_hh2,
                  const float* __restrict__ W_lin, const float* __restrict__ b_lin,
                  float* __restrict__ out)
{
    const int tid  = threadIdx.x;
    const int w    = tid >> 6;        // wave 0..3
    const int lane = tid & 63;
    const int q    = lane >> 4;       // quad
    const int mcol = lane & 15;       // batch column (and A-frag m)
    const int b0   = blockIdx.x * BPB;

    __shared__ unsigned h1s[2][64 * LSTR];   // packed (hi16|lo16); rows 51..63 zero
    __shared__ unsigned h2s[2][64 * LSTR];

    for (int i = tid; i < 64 * LSTR; i += NTHR) {
        h1s[0][i] = 0u; h1s[1][i] = 0u;
        h2s[0][i] = 0u; h2s[1][i] = 0u;
    }

    // ---- persistent weight fragments (AGPR-resident; mfma reads natively) --
    bf16x8 A1h[4][2], A1l[4][2];          // W_hh1 hi/lo  x Ktile
    bf16x8 Aih[4][2], Ail[4][2];          // W_ih2 hi/lo
    bf16x8 Ahh[4][2], Ahl[4][2];          // W_hh2 hi/lo
    f4 bb1[4], bb2[4], wxv[4];
    float c1[4], c2[4];
#pragma unroll
    for (int s = 0; s < 4; ++s) {
        const int t = 4 * s + w;          // row-tile (>=13 -> dummy, zeros)
        const int u = 4 * t + q;          // this lane's unit for slot s
        c1[s] = 0.0f; c2[s] = 0.0f;
#pragma unroll
        for (int kt = 0; kt < 2; ++kt) {
            load_wfrag(W_hh1, t, kt, q, mcol, &A1h[s][kt], &A1l[s][kt]);
            load_wfrag(W_ih2, t, kt, q, mcol, &Aih[s][kt], &Ail[s][kt]);
            load_wfrag(W_hh2, t, kt, q, mcol, &Ahh[s][kt], &Ahl[s][kt]);
        }
#pragma unroll
        for (int j = 0; j < 4; ++j) {     // gate j of unit u (PyTorch row j*H+u)
            const bool v = (u < H);
            bb1[s][j] = v ? (b_ih1[j * H + u] + b_hh1[j * H + u]) : 0.0f;
            bb2[s][j] = v ? (b_ih2[j * H + u] + b_hh2[j * H + u]) : 0.0f;
            wxv[s][j] = v ? W_ih1[j * H + u] : 0.0f;
        }
    }

    float wl[13];                          // wave3: y-dot weights
    if (w == 3) {
#pragma unroll
        for (int i = 0; i < 13; ++i) {
            const int r = q * 13 + i;
            wl[i] = (r < H) ? W_lin[r] : 0.0f;
        }
    }
    const float blin = b_lin[0];

    float xcur = input[(size_t)(b0 + mcol) * TLEN + 0];

    __syncthreads();                       // zeros visible

    for (int k = 0; k <= TLEN; ++k) {
        const int rb   = (k + 1) & 1;      // holds h1(k-1), h2(k-2)
        const int wbuf = k & 1;
        const int kn   = (k + 1 < TLEN) ? (k + 1) : (TLEN - 1);
        const float xnext = input[(size_t)(b0 + mcol) * TLEN + kn];

        // ---- wave3: deferred y(k-2) from h2s[rb] (stable this iter) ----
        if (w == 3 && k >= 2) {
            float yp = 0.0f;
#pragma unroll
            for (int i = 0; i < 13; ++i)
                yp += wl[i] * unpack_f(h2s[rb][(q * 13 + i) * LSTR + mcol]);
            yp += __shfl_xor(yp, 16);
            yp += __shfl_xor(yp, 32);
            if (q == 0) out[(size_t)(b0 + mcol) * TLEN + (k - 2)] = yp + blin;
        }

        // ---- B-frags: lane holds B[k=quad*8+j][n=mcol]; hi+lo bf16 ----
        bf16x8 B1h[2], B1l[2], B2h[2], B2l[2];
#pragma unroll
        for (int kt = 0; kt < 2; ++kt) {
            unsigned r[8];
            union { unsigned u4[4]; bf16x8 v; } Uh, Ul;
#pragma unroll
            for (int j = 0; j < 8; ++j)
                r[j] = h1s[rb][(kt * 32 + q * 8 + j) * LSTR + mcol];
#pragma unroll
            for (int i = 0; i < 4; ++i) {
                Uh.u4[i] = __builtin_amdgcn_perm(r[2 * i + 1], r[2 * i], 0x07060302u);
                Ul.u4[i] = __builtin_amdgcn_perm(r[2 * i + 1], r[2 * i], 0x05040100u);
            }
            B1h[kt] = Uh.v;  B1l[kt] = Ul.v;
#pragma unroll
            for (int j = 0; j < 8; ++j)
                r[j] = h2s[rb][(kt * 32 + q * 8 + j) * LSTR + mcol];
#pragma unroll
            for (int i = 0; i < 4; ++i) {
                Uh.u4[i] = __builtin_amdgcn_perm(r[2 * i + 1], r[2 * i], 0x07060302u);
                Ul.u4[i] = __builtin_amdgcn_perm(r[2 * i + 1], r[2 * i], 0x05040100u);
            }
            B2h[kt] = Uh.v;  B2l[kt] = Ul.v;
        }

        // ---- per row-tile: mfma chains + lane-local acts ----
#pragma unroll
        for (int s = 0; s < 4; ++s) {
            if (4 * s + w >= 13) continue;             // dummy slot (uniform)
            const int u = 4 * (4 * s + w) + q;

            f4 g1 = {0.0f, 0.0f, 0.0f, 0.0f};          // gates1(k)
            MFMA(g1, A1h[s][0], B1h[0]);  MFMA(g1, A1h[s][1], B1h[1]);
            MFMA(g1, A1h[s][0], B1l[0]);  MFMA(g1, A1h[s][1], B1l[1]);
            MFMA(g1, A1l[s][0], B1h[0]);  MFMA(g1, A1l[s][1], B1h[1]);

            f4 g2 = {0.0f, 0.0f, 0.0f, 0.0f};          // gates2(k-1)
            MFMA(g2, Aih[s][0], B1h[0]);  MFMA(g2, Aih[s][1], B1h[1]);
            MFMA(g2, Aih[s][0], B1l[0]);  MFMA(g2, Aih[s][1], B1l[1]);
            MFMA(g2, Ail[s][0], B1h[0]);  MFMA(g2, Ail[s][1], B1h[1]);
            MFMA(g2, Ahh[s][0], B2h[0]);  MFMA(g2, Ahh[s][1], B2h[1]);
            MFMA(g2, Ahh[s][0], B2l[0]);  MFMA(g2, Ahh[s][1], B2l[1]);
            MFMA(g2, Ahl[s][0], B2h[0]);  MFMA(g2, Ahl[s][1], B2h[1]);

            // L1 act (step k): acc reg j = gate j (i,f,g,o) of unit u
            const float i1 = sigm (g1[0] + bb1[s][0] + wxv[s][0] * xcur);
            const float f1 = sigm (g1[1] + bb1[s][1] + wxv[s][1] * xcur);
            const float gg = tanh_(g1[2] + bb1[s][2] + wxv[s][2] * xcur);
            const float o1 = sigm (g1[3] + bb1[s][3] + wxv[s][3] * xcur);
            c1[s] = f1 * c1[s] + i1 * gg;
            const float h1n = o1 * tanh_(c1[s]);
            if (u < H) h1s[wbuf][u * LSTR + mcol] = pack_hl(h1n);

            // L2 act (step k-1; skipped at k=0 so h2(-1) stays 0)
            const float i2 = sigm (g2[0] + bb2[s][0]);
            const float f2 = sigm (g2[1] + bb2[s][1]);
            const float g2g= tanh_(g2[2] + bb2[s][2]);
            const float o2 = sigm (g2[3] + bb2[s][3]);
            if (k != 0) {
                c2[s] = f2 * c2[s] + i2 * g2g;
                const float h2n = o2 * tanh_(c2[s]);
                if (u < H) h2s[wbuf][u * LSTR + mcol] = pack_hl(h2n);
            }
        }

        __syncthreads();                                // the one barrier
        xcur = xnext;
    }

    // epilogue: y(T-1) from h2s[TLEN & 1] (= wbuf at k=TLEN)
    if (w == 3) {
        float yp = 0.0f;
#pragma unroll
        for (int i = 0; i < 13; ++i)
            yp += wl[i] * unpack_f(h2s[TLEN & 1][(q * 13 + i) * LSTR + mcol]);
        yp += __shfl_xor(yp, 16);
        yp += __shfl_xor(yp, 32);
        if (q == 0) out[(size_t)(b0 + mcol) * TLEN + (TLEN - 1)] = yp + blin;
    }
}

extern "C" void kernel_launch(void* const* d_in, const int* in_sizes, int n_in,
                              void* d_out, int out_size, void* d_ws, size_t ws_size,
                              hipStream_t stream)
{
    const float* input = (const float*)d_in[0];
    const float* W_ih1 = (const float*)d_in[1];
    const float* W_hh1 = (const float*)d_in[2];
    const float* b_ih1 = (const float*)d_in[3];
    const float* b_hh1 = (const float*)d_in[4];
    const float* W_ih2 = (const float*)d_in[5];
    const float* W_hh2 = (const float*)d_in[6];
    const float* b_ih2 = (const float*)d_in[7];
    const float* b_hh2 = (const float*)d_in[8];
    const float* W_lin = (const float*)d_in[9];
    const float* b_lin = (const float*)d_in[10];

    float* out = (float*)d_out;

    hipLaunchKernelGGL(lstm2_kernel, dim3(NBLK), dim3(NTHR), 0, stream,
                       input, W_ih1, W_hh1, b_ih1, b_hh1,
                       W_ih2, W_hh2, b_ih2, b_hh2, W_lin, b_lin,
                       out);
}